// Round 6
// baseline (273.147 us; speedup 1.0000x reference)
//
#include <hip/hip_runtime.h>
#include <type_traits>
#include <utility>

#define B_ 4
#define T_ 160
#define S_ 80
#define F_ 640
#define H_ 1024
#define V_ 1024

typedef float f32x4 __attribute__((ext_vector_type(4)));
typedef float f32x16 __attribute__((ext_vector_type(16)));
typedef short s16x8 __attribute__((ext_vector_type(8)));
typedef __bf16 bf16x8_t __attribute__((ext_vector_type(8)));

// ---- MFMA wrappers: hedge between V8s (short) and V8y (__bf16) signatures ----
template <typename T, typename = void>
struct MfmaTakes : std::false_type {};
template <typename T>
struct MfmaTakes<T, std::void_t<decltype(__builtin_amdgcn_mfma_f32_16x16x32_bf16(
    std::declval<T>(), std::declval<T>(), std::declval<f32x4>(), 0, 0, 0))>>
    : std::true_type {};

template <typename S8>
__device__ __forceinline__ f32x4 mfma_bf16_16x16x32(S8 a, S8 b, f32x4 c) {
  if constexpr (MfmaTakes<S8>::value) {
    return __builtin_amdgcn_mfma_f32_16x16x32_bf16(a, b, c, 0, 0, 0);
  } else {
    return __builtin_amdgcn_mfma_f32_16x16x32_bf16(
        __builtin_bit_cast(bf16x8_t, a), __builtin_bit_cast(bf16x8_t, b), c, 0, 0, 0);
  }
}

template <typename T, typename = void>
struct Mfma32Takes : std::false_type {};
template <typename T>
struct Mfma32Takes<T, std::void_t<decltype(__builtin_amdgcn_mfma_f32_32x32x16_bf16(
    std::declval<T>(), std::declval<T>(), std::declval<f32x16>(), 0, 0, 0))>>
    : std::true_type {};

template <typename S8>
__device__ __forceinline__ f32x16 mfma_bf16_32x32x16(S8 a, S8 b, f32x16 c) {
  if constexpr (Mfma32Takes<S8>::value) {
    return __builtin_amdgcn_mfma_f32_32x32x16_bf16(a, b, c, 0, 0, 0);
  } else {
    return __builtin_amdgcn_mfma_f32_32x32x16_bf16(
        __builtin_bit_cast(bf16x8_t, a), __builtin_bit_cast(bf16x8_t, b), c, 0, 0, 0);
  }
}

// fp32 -> bf16 round-to-nearest-even (no NaN in this workload)
__device__ __forceinline__ unsigned short f2bf(float x) {
  unsigned int u = __float_as_uint(x);
  u += 0x7FFFu + ((u >> 16) & 1u);
  return (unsigned short)(u >> 16);
}

// ---------------------------------------------------------------------------
// Kernel 1: cast W1,W2 to bf16 in fragment-contiguous layout [K/8][N][8]
// so a B-fragment (16x16x32 AND 32x32x16 shapes) is one 16B global load.
// ---------------------------------------------------------------------------
__global__ __launch_bounds__(256) void prep_weights(const float* __restrict__ W1,
                                                    const float* __restrict__ W2,
                                                    s16x8* __restrict__ W1p,
                                                    s16x8* __restrict__ W2p) {
  const int NW1 = (F_ / 8) * H_;   // 81920 chunks
  const int NW2 = (H_ / 8) * V_;   // 131072 chunks
  int c = blockIdx.x * 256 + threadIdx.x;
  if (c < NW1) {
    int kg = c >> 10, v = c & 1023;
    s16x8 o;
#pragma unroll
    for (int i = 0; i < 8; ++i) o[i] = (short)f2bf(W1[(kg * 8 + i) * H_ + v]);
    W1p[c] = o;
  } else if (c < NW1 + NW2) {
    int c2 = c - NW1;
    int kg = c2 >> 10, v = c2 & 1023;
    s16x8 o;
#pragma unroll
    for (int i = 0; i < 8; ++i) o[i] = (short)f2bf(W2[(kg * 8 + i) * V_ + v]);
    W2p[c2] = o;
  }
}

// ---------------------------------------------------------------------------
// Kernel 2: P = src@W1 + b1 (640 rows), Q = tgt@W1 (320 rows), fp32 out.
// 15 WGs x 512 thr; BM=64, 8 waves col-split (128 cols each); 16x16x32 MFMA.
// (~10 us; not the bottleneck — unchanged from R5.)
// ---------------------------------------------------------------------------
__global__ __launch_bounds__(512, 2) void pq_gemm(const float* __restrict__ src,
                                                  const float* __restrict__ tgt,
                                                  const s16x8* __restrict__ W1p,
                                                  const float* __restrict__ b1,
                                                  float* __restrict__ P,
                                                  float* __restrict__ Q) {
  __shared__ s16x8 a_lds[64 * 80];  // 80 KB: rows m, 80 k-chunks, swizzled
  const int tid = threadIdx.x;
  const int wr = blockIdx.x;
  const int r0 = wr * 64;
  const bool isP = (wr < 10);  // rows 0..639 are src, 640..959 are tgt

  for (int c = tid; c < 64 * 80; c += 512) {
    int m = c / 80, kg8 = c - m * 80;
    int R = r0 + m;
    const float* rowp = isP ? (src + R * F_) : (tgt + (R - 640) * F_);
    const f32x4* p4 = (const f32x4*)(rowp + kg8 * 8);
    f32x4 x0 = p4[0], x1 = p4[1];
    s16x8 o;
#pragma unroll
    for (int i = 0; i < 4; ++i) o[i] = (short)f2bf(x0[i]);
#pragma unroll
    for (int i = 0; i < 4; ++i) o[4 + i] = (short)f2bf(x1[i]);
    a_lds[m * 80 + (kg8 ^ (m & 7))] = o;
  }
  __syncthreads();

  const int l = tid & 63, wv = tid >> 6;
  const int g = l >> 4, cl = l & 15;
  const f32x4 zero = {0.f, 0.f, 0.f, 0.f};
  f32x4 acc[4][8];
#pragma unroll
  for (int rt = 0; rt < 4; ++rt)
#pragma unroll
    for (int ct = 0; ct < 8; ++ct) acc[rt][ct] = zero;

  const s16x8* bbase = W1p + g * 1024 + wv * 128 + cl;
  s16x8 bA[8], bB[8], af[4];
#pragma unroll
  for (int ct = 0; ct < 8; ++ct) bA[ct] = bbase[ct * 16];

  for (int ks = 0; ks < 20; ks += 2) {
#pragma unroll
    for (int ct = 0; ct < 8; ++ct) bB[ct] = bbase[(ks + 1) * 4096 + ct * 16];
#pragma unroll
    for (int rt = 0; rt < 4; ++rt) {
      int m = rt * 16 + cl;
      af[rt] = a_lds[m * 80 + ((ks * 4 + g) ^ (m & 7))];
    }
#pragma unroll
    for (int ct = 0; ct < 8; ++ct)
#pragma unroll
      for (int rt = 0; rt < 4; ++rt)
        acc[rt][ct] = mfma_bf16_16x16x32(af[rt], bA[ct], acc[rt][ct]);
    int ksn = (ks + 2 < 20) ? (ks + 2) : 0;  // dummy reload on last iter
#pragma unroll
    for (int ct = 0; ct < 8; ++ct) bA[ct] = bbase[ksn * 4096 + ct * 16];
#pragma unroll
    for (int rt = 0; rt < 4; ++rt) {
      int m = rt * 16 + cl;
      af[rt] = a_lds[m * 80 + (((ks + 1) * 4 + g) ^ (m & 7))];
    }
#pragma unroll
    for (int ct = 0; ct < 8; ++ct)
#pragma unroll
      for (int rt = 0; rt < 4; ++rt)
        acc[rt][ct] = mfma_bf16_16x16x32(af[rt], bB[ct], acc[rt][ct]);
  }

  float b1v[8];
#pragma unroll
  for (int ct = 0; ct < 8; ++ct) b1v[ct] = isP ? b1[wv * 128 + ct * 16 + cl] : 0.f;
  float* outbase = isP ? P : Q;
  const int orow0 = isP ? r0 : (r0 - 640);
#pragma unroll
  for (int rt = 0; rt < 4; ++rt) {
#pragma unroll
    for (int j = 0; j < 4; ++j) {
      int row = rt * 16 + g * 4 + j;
      float* op = outbase + (size_t)(orow0 + row) * H_ + wv * 128 + cl;
#pragma unroll
      for (int ct = 0; ct < 8; ++ct) op[ct * 16] = acc[rt][ct][j] + b1v[ct];
    }
  }
}

// ---------------------------------------------------------------------------
// Kernel 3: fused h-build + GEMM2 + bias + log_softmax.
// 800 WGs x 1024 threads (16 waves), 64-row x 1024-col tile, wave owns 64
// cols as 2 col-tiles of 32. MFMA 32x32x16 (higher rate, and frag regs are
// HALF of 16x16x32 per k-step) -> fits a depth-2 B-prefetch pipeline inside
// the hard 128 reg/wave cap (1 WG/CU x 16 waves): acc 4x16=64 + 2x8 buffer
// + 2x8 incoming + A 16 + addr ~ 120. No spill (R2-R4 lesson: the canary is
// FETCH_SIZE/WRITE_SIZE inflation).
// Fragment layouts (K-doubled 32x32x8 pattern, same doubling as verified
// 16x16x32): A row=lane&31, k=(lane>>5)*8+i; B col=lane&31, same k;
// C/D col=lane&31, row=(reg&3)+8*(reg>>2)+4*(lane>>5).
// ---------------------------------------------------------------------------
__global__ __launch_bounds__(1024, 4) void joint_main(const float* __restrict__ Pm,
                                                      const float* __restrict__ Qm,
                                                      const s16x8* __restrict__ W2p,
                                                      const float* __restrict__ b2,
                                                      float* __restrict__ out) {
  __shared__ s16x8 h_lds[64 * 128];  // 128 KB
  const int tid = threadIdx.x;
  int bx = blockIdx.x;
  int bid = (bx & 7) * 100 + (bx >> 3);  // XCD-contiguous swizzle (800 % 8 == 0)
  const int b = bid / 200;
  int rem = bid - b * 200;
  const int t0 = (rem / 10) * 8;
  const int s0 = (rem - (rem / 10) * 10) * 8;

  // build h = relu(P[t] + Q[s]) as bf16, swizzled: chunk (m,kg8) -> slot kg8^(m&7)
  for (int c = tid; c < 64 * 128; c += 1024) {
    int m = c >> 7, kg8 = c & 127;
    int dt = m >> 3, ds = m & 7;
    const f32x4* p4 = (const f32x4*)(Pm + (size_t)(b * T_ + t0 + dt) * H_ + kg8 * 8);
    const f32x4* q4 = (const f32x4*)(Qm + (size_t)(b * S_ + s0 + ds) * H_ + kg8 * 8);
    f32x4 x0 = p4[0] + q4[0];
    f32x4 x1 = p4[1] + q4[1];
    s16x8 o;
#pragma unroll
    for (int i = 0; i < 4; ++i) o[i] = (short)f2bf(fmaxf(x0[i], 0.f));
#pragma unroll
    for (int i = 0; i < 4; ++i) o[4 + i] = (short)f2bf(fmaxf(x1[i], 0.f));
    h_lds[m * 128 + (kg8 ^ (m & 7))] = o;
  }
  __syncthreads();

  const int l = tid & 63, wv = tid >> 6;  // wv 0..15 owns cols [wv*64, wv*64+64)
  const int c32 = l & 31, hf = l >> 5;
  const int sw0 = c32 & 7;  // (rt*32+c32)&7 == c32&7 for both row-tiles

  f32x16 acc00 = {}, acc01 = {}, acc10 = {}, acc11 = {};

  // B base: k-chunk kg = ks*2 + hf, col = wv*64 + ct*32 + c32
  const s16x8* wb = W2p + hf * 1024 + wv * 64 + c32;
  // A bases: row m = rt*32 + c32
  const s16x8* ha0 = h_lds + c32 * 128;
  const s16x8* ha1 = h_lds + (32 + c32) * 128;

  // depth-2 prefetch pipeline over 64 k16-steps (2 steps per iteration)
  s16x8 bA0 = wb[0], bA1 = wb[32];
  s16x8 bB0 = wb[2048], bB1 = wb[2048 + 32];
  for (int ks = 0; ks < 64; ks += 2) {
    int i2 = (ks + 2 < 64) ? ks + 2 : 0;  // dummy reload on last iter
    int i3 = (ks + 3 < 64) ? ks + 3 : 0;
    s16x8 nA0 = wb[i2 * 2048], nA1 = wb[i2 * 2048 + 32];
    s16x8 nB0 = wb[i3 * 2048], nB1 = wb[i3 * 2048 + 32];
    int k0 = (ks * 2 + hf) ^ sw0;
    s16x8 a0 = ha0[k0], a1 = ha1[k0];
    acc00 = mfma_bf16_32x32x16(a0, bA0, acc00);
    acc10 = mfma_bf16_32x32x16(a1, bA0, acc10);
    acc01 = mfma_bf16_32x32x16(a0, bA1, acc01);
    acc11 = mfma_bf16_32x32x16(a1, bA1, acc11);
    int k1 = k0 ^ 2;  // (ks+1)*2+hf ^ sw0  (bit1 of ks*2+hf is 0 for even ks)
    s16x8 c0 = ha0[k1], c1 = ha1[k1];
    acc00 = mfma_bf16_32x32x16(c0, bB0, acc00);
    acc10 = mfma_bf16_32x32x16(c1, bB0, acc10);
    acc01 = mfma_bf16_32x32x16(c0, bB1, acc01);
    acc11 = mfma_bf16_32x32x16(c1, bB1, acc11);
    bA0 = nA0; bA1 = nA1; bB0 = nB0; bB1 = nB1;
  }

  // ---- epilogue: +b2, row-wise log_softmax across 16 waves, store ----
  __syncthreads();  // all waves done reading h before overlaying reductions
  float* redm = reinterpret_cast<float*>(h_lds);  // [16 waves][64 rows]
  float* gmbuf = redm + 1024;                     // [64 rows] global max
  float* reds = gmbuf + 64;                       // [16 waves][64 rows]
  float* lsebuf = reds + 1024;                    // [64 rows]

  const float bv0 = b2[wv * 64 + c32];
  const float bv1 = b2[wv * 64 + 32 + c32];
#pragma unroll
  for (int r = 0; r < 16; ++r) {
    acc00[r] += bv0; acc10[r] += bv0;
    acc01[r] += bv1; acc11[r] += bv1;
  }

  // phase 1: per-wave per-row max (rows: rt*32 + (r&3)+8*(r>>2)+4*hf)
#pragma unroll
  for (int r = 0; r < 16; ++r) {
    float m0 = fmaxf(acc00[r], acc01[r]);
    float m1 = fmaxf(acc10[r], acc11[r]);
#pragma unroll
    for (int msk = 1; msk < 32; msk <<= 1) {
      m0 = fmaxf(m0, __shfl_xor(m0, msk, 64));
      m1 = fmaxf(m1, __shfl_xor(m1, msk, 64));
    }
    if (c32 == 0) {
      int rr = (r & 3) + 8 * (r >> 2) + 4 * hf;
      redm[wv * 64 + rr] = m0;
      redm[wv * 64 + 32 + rr] = m1;
    }
  }
  __syncthreads();

  // phase 2: global row max (threads 0..63)
  if (tid < 64) {
    float mx = redm[tid];
#pragma unroll
    for (int w = 1; w < 16; ++w) mx = fmaxf(mx, redm[w * 64 + tid]);
    gmbuf[tid] = mx;
  }
  __syncthreads();

  // phase 3: per-wave per-row sum of exp
#pragma unroll
  for (int rt = 0; rt < 2; ++rt) {
#pragma unroll
    for (int q = 0; q < 4; ++q) {
      int rowb = rt * 32 + 8 * q + 4 * hf;
      f32x4 gm4 = *(const f32x4*)&gmbuf[rowb];
      f32x4 ps;
#pragma unroll
      for (int j = 0; j < 4; ++j) {
        int r = q * 4 + j;
        float e0 = (rt == 0) ? __expf(acc00[r] - gm4[j]) + __expf(acc01[r] - gm4[j])
                             : __expf(acc10[r] - gm4[j]) + __expf(acc11[r] - gm4[j]);
        ps[j] = e0;
      }
#pragma unroll
      for (int msk = 1; msk < 32; msk <<= 1) {
#pragma unroll
        for (int j = 0; j < 4; ++j) ps[j] += __shfl_xor(ps[j], msk, 64);
      }
      if (c32 == 0) *(f32x4*)&reds[wv * 64 + rowb] = ps;
    }
  }
  __syncthreads();

  // phase 4: finalize lse (threads 0..63)
  if (tid < 64) {
    float s = reds[tid];
#pragma unroll
    for (int w = 1; w < 16; ++w) s += reds[w * 64 + tid];
    lsebuf[tid] = gmbuf[tid] + __logf(s);
  }
  __syncthreads();

  // phase 5: store out = logit - lse
#pragma unroll
  for (int rt = 0; rt < 2; ++rt) {
#pragma unroll
    for (int q = 0; q < 4; ++q) {
      int rowb = rt * 32 + 8 * q + 4 * hf;
      f32x4 lse4 = *(const f32x4*)&lsebuf[rowb];
      int n0 = (b * T_ + t0 + rt * 4 + q) * S_ + s0 + 4 * hf;
#pragma unroll
      for (int j = 0; j < 4; ++j) {
        int r = q * 4 + j;
        float* op = out + (size_t)(n0 + j) * V_ + wv * 64 + c32;
        if (rt == 0) {
          op[0] = acc00[r] - lse4[j];
          op[32] = acc01[r] - lse4[j];
        } else {
          op[0] = acc10[r] - lse4[j];
          op[32] = acc11[r] - lse4[j];
        }
      }
    }
  }
}

// ---------------------------------------------------------------------------
extern "C" void kernel_launch(void* const* d_in, const int* in_sizes, int n_in,
                              void* d_out, int out_size, void* d_ws, size_t ws_size,
                              hipStream_t stream) {
  const float* src = (const float*)d_in[0];  // [4,160,640]
  const float* tgt = (const float*)d_in[1];  // [4,80,640]
  const float* W1  = (const float*)d_in[2];  // [640,1024]
  const float* b1  = (const float*)d_in[3];  // [1024]
  const float* W2  = (const float*)d_in[4];  // [1024,1024]
  const float* b2  = (const float*)d_in[5];  // [1024]
  float* out = (float*)d_out;

  char* ws = (char*)d_ws;
  s16x8* W1p = (s16x8*)(ws);             // 1,310,720 B
  s16x8* W2p = (s16x8*)(ws + 1310720);   // 2,097,152 B
  float* P   = (float*)(ws + 3407872);   // 2,621,440 B  (src@W1 + b1)
  float* Q   = (float*)(ws + 6029312);   // 1,310,720 B  (tgt@W1)
  // total ws use: 7,340,032 B

  prep_weights<<<832, 256, 0, stream>>>(W1, W2, W1p, W2p);
  pq_gemm<<<15, 512, 0, stream>>>(src, tgt, W1p, b1, P, Q);
  joint_main<<<800, 1024, 0, stream>>>(P, Q, W2p, b2, out);
}

// Round 7
// 201.983 us; speedup vs baseline: 1.3523x; 1.3523x over previous
//
#include <hip/hip_runtime.h>
#include <type_traits>
#include <utility>

#define B_ 4
#define T_ 160
#define S_ 80
#define F_ 640
#define H_ 1024
#define V_ 1024

typedef float f32x4 __attribute__((ext_vector_type(4)));
typedef short s16x8 __attribute__((ext_vector_type(8)));
typedef __bf16 bf16x8_t __attribute__((ext_vector_type(8)));

// ---- MFMA wrapper: hedge between V8s (short) and V8y (__bf16) builtin signatures ----
template <typename T, typename = void>
struct MfmaTakes : std::false_type {};
template <typename T>
struct MfmaTakes<T, std::void_t<decltype(__builtin_amdgcn_mfma_f32_16x16x32_bf16(
    std::declval<T>(), std::declval<T>(), std::declval<f32x4>(), 0, 0, 0))>>
    : std::true_type {};

template <typename S8>
__device__ __forceinline__ f32x4 mfma_bf16_16x16x32(S8 a, S8 b, f32x4 c) {
  if constexpr (MfmaTakes<S8>::value) {
    return __builtin_amdgcn_mfma_f32_16x16x32_bf16(a, b, c, 0, 0, 0);
  } else {
    return __builtin_amdgcn_mfma_f32_16x16x32_bf16(
        __builtin_bit_cast(bf16x8_t, a), __builtin_bit_cast(bf16x8_t, b), c, 0, 0, 0);
  }
}

// fp32 -> bf16 round-to-nearest-even (no NaN in this workload)
__device__ __forceinline__ unsigned short f2bf(float x) {
  unsigned int u = __float_as_uint(x);
  u += 0x7FFFu + ((u >> 16) & 1u);
  return (unsigned short)(u >> 16);
}

// ---------------------------------------------------------------------------
// Kernel 1: cast W1,W2 to bf16 in fragment-contiguous layout [K/8][N][8]
// so a B-fragment for mfma_16x16x32 is one 16B global load.
// ---------------------------------------------------------------------------
__global__ __launch_bounds__(256) void prep_weights(const float* __restrict__ W1,
                                                    const float* __restrict__ W2,
                                                    s16x8* __restrict__ W1p,
                                                    s16x8* __restrict__ W2p) {
  const int NW1 = (F_ / 8) * H_;   // 81920 chunks
  const int NW2 = (H_ / 8) * V_;   // 131072 chunks
  int c = blockIdx.x * 256 + threadIdx.x;
  if (c < NW1) {
    int kg = c >> 10, v = c & 1023;
    s16x8 o;
#pragma unroll
    for (int i = 0; i < 8; ++i) o[i] = (short)f2bf(W1[(kg * 8 + i) * H_ + v]);
    W1p[c] = o;
  } else if (c < NW1 + NW2) {
    int c2 = c - NW1;
    int kg = c2 >> 10, v = c2 & 1023;
    s16x8 o;
#pragma unroll
    for (int i = 0; i < 8; ++i) o[i] = (short)f2bf(W2[(kg * 8 + i) * V_ + v]);
    W2p[c2] = o;
  }
}

// ---------------------------------------------------------------------------
// Kernel 2: P = src@W1 + b1 (640 rows), Q = tgt@W1 (320 rows), fp32 out.
// 15 WGs x 512 thr; BM=64, 8 waves col-split (128 cols each); 16x16x32 MFMA.
// (~10 us; not the bottleneck — unchanged.)
// ---------------------------------------------------------------------------
__global__ __launch_bounds__(512, 2) void pq_gemm(const float* __restrict__ src,
                                                  const float* __restrict__ tgt,
                                                  const s16x8* __restrict__ W1p,
                                                  const float* __restrict__ b1,
                                                  float* __restrict__ P,
                                                  float* __restrict__ Q) {
  __shared__ s16x8 a_lds[64 * 80];  // 80 KB: rows m, 80 k-chunks, swizzled
  const int tid = threadIdx.x;
  const int wr = blockIdx.x;
  const int r0 = wr * 64;
  const bool isP = (wr < 10);  // rows 0..639 are src, 640..959 are tgt

  for (int c = tid; c < 64 * 80; c += 512) {
    int m = c / 80, kg8 = c - m * 80;
    int R = r0 + m;
    const float* rowp = isP ? (src + R * F_) : (tgt + (R - 640) * F_);
    const f32x4* p4 = (const f32x4*)(rowp + kg8 * 8);
    f32x4 x0 = p4[0], x1 = p4[1];
    s16x8 o;
#pragma unroll
    for (int i = 0; i < 4; ++i) o[i] = (short)f2bf(x0[i]);
#pragma unroll
    for (int i = 0; i < 4; ++i) o[4 + i] = (short)f2bf(x1[i]);
    a_lds[m * 80 + (kg8 ^ (m & 7))] = o;
  }
  __syncthreads();

  const int l = tid & 63, wv = tid >> 6;
  const int g = l >> 4, cl = l & 15;
  const f32x4 zero = {0.f, 0.f, 0.f, 0.f};
  f32x4 acc[4][8];
#pragma unroll
  for (int rt = 0; rt < 4; ++rt)
#pragma unroll
    for (int ct = 0; ct < 8; ++ct) acc[rt][ct] = zero;

  const s16x8* bbase = W1p + g * 1024 + wv * 128 + cl;
  s16x8 bA[8], bB[8], af[4];
#pragma unroll
  for (int ct = 0; ct < 8; ++ct) bA[ct] = bbase[ct * 16];

  for (int ks = 0; ks < 20; ks += 2) {
#pragma unroll
    for (int ct = 0; ct < 8; ++ct) bB[ct] = bbase[(ks + 1) * 4096 + ct * 16];
#pragma unroll
    for (int rt = 0; rt < 4; ++rt) {
      int m = rt * 16 + cl;
      af[rt] = a_lds[m * 80 + ((ks * 4 + g) ^ (m & 7))];
    }
#pragma unroll
    for (int ct = 0; ct < 8; ++ct)
#pragma unroll
      for (int rt = 0; rt < 4; ++rt)
        acc[rt][ct] = mfma_bf16_16x16x32(af[rt], bA[ct], acc[rt][ct]);
    int ksn = (ks + 2 < 20) ? (ks + 2) : 0;  // dummy reload on last iter
#pragma unroll
    for (int ct = 0; ct < 8; ++ct) bA[ct] = bbase[ksn * 4096 + ct * 16];
#pragma unroll
    for (int rt = 0; rt < 4; ++rt) {
      int m = rt * 16 + cl;
      af[rt] = a_lds[m * 80 + (((ks + 1) * 4 + g) ^ (m & 7))];
    }
#pragma unroll
    for (int ct = 0; ct < 8; ++ct)
#pragma unroll
      for (int rt = 0; rt < 4; ++rt)
        acc[rt][ct] = mfma_bf16_16x16x32(af[rt], bB[ct], acc[rt][ct]);
  }

  float b1v[8];
#pragma unroll
  for (int ct = 0; ct < 8; ++ct) b1v[ct] = isP ? b1[wv * 128 + ct * 16 + cl] : 0.f;
  float* outbase = isP ? P : Q;
  const int orow0 = isP ? r0 : (r0 - 640);
#pragma unroll
  for (int rt = 0; rt < 4; ++rt) {
#pragma unroll
    for (int j = 0; j < 4; ++j) {
      int row = rt * 16 + g * 4 + j;
      float* op = outbase + (size_t)(orow0 + row) * H_ + wv * 128 + cl;
#pragma unroll
      for (int ct = 0; ct < 8; ++ct) op[ct * 16] = acc[rt][ct][j] + b1v[ct];
    }
  }
}

// ---------------------------------------------------------------------------
// Kernel 3: fused h-build + GEMM2 + bias + log_softmax.
// R7 STRUCTURE: 1600 WGs x 512 thr (8 waves). Tile = 32 rows (4t x 8s) x
// 1024 cols; h_lds = EXACTLY 64 KB -> 2 WGs/CU. The two co-resident WGs
// share no barrier, so one WG's MFMA loop fills the other's h-build /
// K-loop-latency / store stalls (R5/R6 showed 1 WG/CU serializes phases:
// MFMA busy-time was identical 46 us in both, rest = stall).
// Per wave: 32 rows x 128 cols -> acc[2][8] = 64 AGPR + ~52 VGPR, same
// proven no-spill profile as R5 (canary: FETCH/WRITE_SIZE exact).
// ---------------------------------------------------------------------------
__global__ __launch_bounds__(512, 2) void joint_main(const float* __restrict__ Pm,
                                                     const float* __restrict__ Qm,
                                                     const s16x8* __restrict__ W2p,
                                                     const float* __restrict__ b2,
                                                     float* __restrict__ out) {
  __shared__ s16x8 h_lds[32 * 128];  // 64 KB exactly -> 2 WGs/CU
  const int tid = threadIdx.x;
  int bx = blockIdx.x;
  int bid = (bx & 7) * 200 + (bx >> 3);  // XCD-contiguous swizzle (1600 % 8 == 0)
  const int b = bid / 400;
  int rem = bid - b * 400;
  const int t0 = (rem / 10) * 4;
  const int s0 = (rem - (rem / 10) * 10) * 8;

  // build h = relu(P[t] + Q[s]) as bf16, swizzled: chunk (m,kg8) -> slot kg8^(m&7)
  for (int c = tid; c < 32 * 128; c += 512) {
    int m = c >> 7, kg8 = c & 127;
    int dt = m >> 3, ds = m & 7;
    const f32x4* p4 = (const f32x4*)(Pm + (size_t)(b * T_ + t0 + dt) * H_ + kg8 * 8);
    const f32x4* q4 = (const f32x4*)(Qm + (size_t)(b * S_ + s0 + ds) * H_ + kg8 * 8);
    f32x4 x0 = p4[0] + q4[0];
    f32x4 x1 = p4[1] + q4[1];
    s16x8 o;
#pragma unroll
    for (int i = 0; i < 4; ++i) o[i] = (short)f2bf(fmaxf(x0[i], 0.f));
#pragma unroll
    for (int i = 0; i < 4; ++i) o[4 + i] = (short)f2bf(fmaxf(x1[i], 0.f));
    h_lds[m * 128 + (kg8 ^ (m & 7))] = o;
  }
  __syncthreads();

  const int l = tid & 63, wv = tid >> 6;   // wv in 0..7, owns cols [wv*128, +128)
  const int g = l >> 4, cl = l & 15;
  const f32x4 zero = {0.f, 0.f, 0.f, 0.f};
  f32x4 acc[2][8];
#pragma unroll
  for (int rt = 0; rt < 2; ++rt)
#pragma unroll
    for (int ct = 0; ct < 8; ++ct) acc[rt][ct] = zero;

  const s16x8* bbase = W2p + g * 1024 + wv * 128 + cl;
  s16x8 bA[8], bB[8], af[2];
#pragma unroll
  for (int ct = 0; ct < 8; ++ct) bA[ct] = bbase[ct * 16];

  for (int ks = 0; ks < 32; ks += 2) {
#pragma unroll
    for (int ct = 0; ct < 8; ++ct) bB[ct] = bbase[(ks + 1) * 4096 + ct * 16];
#pragma unroll
    for (int rt = 0; rt < 2; ++rt) {
      int m = rt * 16 + cl;
      af[rt] = h_lds[m * 128 + ((ks * 4 + g) ^ (m & 7))];
    }
#pragma unroll
    for (int ct = 0; ct < 8; ++ct)
#pragma unroll
      for (int rt = 0; rt < 2; ++rt)
        acc[rt][ct] = mfma_bf16_16x16x32(af[rt], bA[ct], acc[rt][ct]);
    int ksn = (ks + 2 < 32) ? (ks + 2) : 0;  // dummy reload on last iter
#pragma unroll
    for (int ct = 0; ct < 8; ++ct) bA[ct] = bbase[ksn * 4096 + ct * 16];
#pragma unroll
    for (int rt = 0; rt < 2; ++rt) {
      int m = rt * 16 + cl;
      af[rt] = h_lds[m * 128 + (((ks + 1) * 4 + g) ^ (m & 7))];
    }
#pragma unroll
    for (int ct = 0; ct < 8; ++ct)
#pragma unroll
      for (int rt = 0; rt < 2; ++rt)
        acc[rt][ct] = mfma_bf16_16x16x32(af[rt], bB[ct], acc[rt][ct]);
  }

  // ---- epilogue: +b2, row-wise log_softmax across 8 waves, store ----
  __syncthreads();  // all waves done reading h before overlaying reductions
  float* redm = reinterpret_cast<float*>(h_lds);  // [8 waves][32 rows]
  float* reds = redm + 256;                       // [8 waves][32 rows]
  float* gmbuf = reds + 256;                      // [32 rows]
  float* lsebuf = gmbuf + 32;                     // [32 rows]

  // bias
#pragma unroll
  for (int ct = 0; ct < 8; ++ct) {
    float bv = b2[wv * 128 + ct * 16 + cl];
#pragma unroll
    for (int rt = 0; rt < 2; ++rt)
#pragma unroll
      for (int j = 0; j < 4; ++j) acc[rt][ct][j] += bv;
  }

  // per-wave per-row max -> redm (scalar chain, one row at a time)
#pragma unroll
  for (int rt = 0; rt < 2; ++rt)
#pragma unroll
    for (int j = 0; j < 4; ++j) {
      float mx = acc[rt][0][j];
#pragma unroll
      for (int ct = 1; ct < 8; ++ct) mx = fmaxf(mx, acc[rt][ct][j]);
#pragma unroll
      for (int msk = 1; msk < 16; msk <<= 1) mx = fmaxf(mx, __shfl_xor(mx, msk, 64));
      if (cl == 0) redm[wv * 32 + rt * 16 + g * 4 + j] = mx;
    }
  __syncthreads();

  // global row max (threads 0..31)
  if (tid < 32) {
    float mx = redm[tid];
#pragma unroll
    for (int w = 1; w < 8; ++w) mx = fmaxf(mx, redm[w * 32 + tid]);
    gmbuf[tid] = mx;
  }
  __syncthreads();

  // per-wave per-row partial sumexp vs global max -> reds
#pragma unroll
  for (int rt = 0; rt < 2; ++rt)
#pragma unroll
    for (int j = 0; j < 4; ++j) {
      int row = rt * 16 + g * 4 + j;
      float gm = gmbuf[row];
      float ps = 0.f;
#pragma unroll
      for (int ct = 0; ct < 8; ++ct) ps += __expf(acc[rt][ct][j] - gm);
#pragma unroll
      for (int msk = 1; msk < 16; msk <<= 1) ps += __shfl_xor(ps, msk, 64);
      if (cl == 0) reds[wv * 32 + row] = ps;
    }
  __syncthreads();

  // finalize lse per row (threads 0..31)
  if (tid < 32) {
    float s = reds[tid];
#pragma unroll
    for (int w = 1; w < 8; ++w) s += reds[w * 32 + tid];
    lsebuf[tid] = gmbuf[tid] + __logf(s);
  }
  __syncthreads();

  // store
#pragma unroll
  for (int rt = 0; rt < 2; ++rt)
#pragma unroll
    for (int j = 0; j < 4; ++j) {
      int row = rt * 16 + g * 4 + j;
      float lse = lsebuf[row];
      int n = (b * T_ + t0 + (row >> 3)) * S_ + s0 + (row & 7);
      float* op = out + (size_t)n * V_ + wv * 128 + cl;
#pragma unroll
      for (int ct = 0; ct < 8; ++ct) op[ct * 16] = acc[rt][ct][j] - lse;
    }
}

// ---------------------------------------------------------------------------
extern "C" void kernel_launch(void* const* d_in, const int* in_sizes, int n_in,
                              void* d_out, int out_size, void* d_ws, size_t ws_size,
                              hipStream_t stream) {
  const float* src = (const float*)d_in[0];  // [4,160,640]
  const float* tgt = (const float*)d_in[1];  // [4,80,640]
  const float* W1  = (const float*)d_in[2];  // [640,1024]
  const float* b1  = (const float*)d_in[3];  // [1024]
  const float* W2  = (const float*)d_in[4];  // [1024,1024]
  const float* b2  = (const float*)d_in[5];  // [1024]
  float* out = (float*)d_out;

  char* ws = (char*)d_ws;
  s16x8* W1p = (s16x8*)(ws);             // 1,310,720 B
  s16x8* W2p = (s16x8*)(ws + 1310720);   // 2,097,152 B
  float* P   = (float*)(ws + 3407872);   // 2,621,440 B  (src@W1 + b1)
  float* Q   = (float*)(ws + 6029312);   // 1,310,720 B  (tgt@W1)
  // total ws use: 7,340,032 B

  prep_weights<<<832, 256, 0, stream>>>(W1, W2, W1p, W2p);
  pq_gemm<<<15, 512, 0, stream>>>(src, tgt, W1p, b1, P, Q);
  joint_main<<<1600, 512, 0, stream>>>(P, Q, W2p, b2, out);
}